// Round 1
// baseline (126.965 us; speedup 1.0000x reference)
//
#include <hip/hip_runtime.h>

// OhemCELoss on MI355X (gfx950).
// Layout: pred [B=16, C=5, H=768, W=768] f32; gt [B,H,W] int32; ratio scalar int.
// Pass 1 (k_ce_pass): streaming per-pixel 5-class CE; accumulate
//   {loss_pos, sum_neg_all, cnt_pos, cnt_neg} via block reduce + double atomics.
// Pass 2 (k_finalize, 1 block): n_neg = min(cnt_neg, int(ratio*cnt_pos)).
//   Common case (n_neg == cnt_neg, guaranteed by this input's label stats):
//   out = (loss_pos + sum_neg_all) / (cnt_pos + n_neg).
//   General fallback: exact k-th-largest via 4-round radix select on monotone
//   float->uint keys (recomputes CE; slow, single block, never taken here).

static constexpr int B_ = 16, C_ = 5, H_ = 768, W_ = 768;
static constexpr int HW_ = H_ * W_;          // 589824 (divisible by 4)
static constexpr int NPIX_ = B_ * HW_;       // 9,437,184
static constexpr int NQUAD_ = NPIX_ / 4;

struct WsHeader {
    double loss_pos;   // sum CE over positives
    double sum_neg;    // sum CE over ALL negatives
    unsigned cnt_pos;
    unsigned cnt_neg;
    unsigned pad[2];
};

__device__ __forceinline__ unsigned f2ord(float f) {
    unsigned u = __float_as_uint(f);
    return (u & 0x80000000u) ? ~u : (u | 0x80000000u);
}
__device__ __forceinline__ float ord2f(unsigned o) {
    unsigned v = (o & 0x80000000u) ? (o & 0x7FFFFFFFu) : ~o;
    return __uint_as_float(v);
}

__device__ __forceinline__ float pixel_ce(const float* __restrict__ pred, int p, int t) {
    const int b = p / HW_;
    const int hw = p - b * HW_;
    const float* base = pred + (size_t)b * (C_ * HW_) + hw;
    const float x0 = base[0], x1 = base[HW_], x2 = base[2 * HW_],
                x3 = base[3 * HW_], x4 = base[4 * HW_];
    const float m = fmaxf(fmaxf(fmaxf(x0, x1), fmaxf(x2, x3)), x4);
    const float lse = m + logf(expf(x0 - m) + expf(x1 - m) + expf(x2 - m) +
                               expf(x3 - m) + expf(x4 - m));
    const float xt = (t == 0) ? x0 : (t == 1) ? x1 : (t == 2) ? x2 : (t == 3) ? x3 : x4;
    return lse - xt;
}

__global__ __launch_bounds__(256) void k_ce_pass(const float* __restrict__ pred,
                                                 const int* __restrict__ gt,
                                                 WsHeader* __restrict__ ws) {
    float lp = 0.f, ln = 0.f;
    unsigned cp = 0u, cn = 0u;
    const int stride = gridDim.x * blockDim.x;
    for (int q = blockIdx.x * blockDim.x + threadIdx.x; q < NQUAD_; q += stride) {
        const int p = q << 2;
        const int b = p / HW_;          // all 4 pixels share b (HW_ % 4 == 0)
        const int hw = p - b * HW_;
        const float* base = pred + (size_t)b * (C_ * HW_) + hw;
        const float4 v0 = *reinterpret_cast<const float4*>(base);
        const float4 v1 = *reinterpret_cast<const float4*>(base + HW_);
        const float4 v2 = *reinterpret_cast<const float4*>(base + 2 * HW_);
        const float4 v3 = *reinterpret_cast<const float4*>(base + 3 * HW_);
        const float4 v4 = *reinterpret_cast<const float4*>(base + 4 * HW_);
        const int4 t4 = *reinterpret_cast<const int4*>(gt + p);
        const float a0[4] = {v0.x, v0.y, v0.z, v0.w};
        const float a1[4] = {v1.x, v1.y, v1.z, v1.w};
        const float a2[4] = {v2.x, v2.y, v2.z, v2.w};
        const float a3[4] = {v3.x, v3.y, v3.z, v3.w};
        const float a4[4] = {v4.x, v4.y, v4.z, v4.w};
        const int tt[4] = {t4.x, t4.y, t4.z, t4.w};
#pragma unroll
        for (int j = 0; j < 4; ++j) {
            const float x0 = a0[j], x1 = a1[j], x2 = a2[j], x3 = a3[j], x4 = a4[j];
            const float m = fmaxf(fmaxf(fmaxf(x0, x1), fmaxf(x2, x3)), x4);
            const float se = expf(x0 - m) + expf(x1 - m) + expf(x2 - m) +
                             expf(x3 - m) + expf(x4 - m);
            const float lse = m + logf(se);
            const int t = tt[j];
            const float xt = (t == 0) ? x0 : (t == 1) ? x1 : (t == 2) ? x2
                           : (t == 3) ? x3 : x4;
            const float ce = lse - xt;
            if ((unsigned)(t - 1) <= 2u) { lp += ce; ++cp; }
            else                          { ln += ce; ++cn; }
        }
    }
    // wave64 reduce
#pragma unroll
    for (int off = 32; off > 0; off >>= 1) {
        lp += __shfl_down(lp, off);
        ln += __shfl_down(ln, off);
        cp += __shfl_down(cp, off);
        cn += __shfl_down(cn, off);
    }
    __shared__ float s_lp[4], s_ln[4];
    __shared__ unsigned s_cp[4], s_cn[4];
    const int wid = threadIdx.x >> 6;
    const int lane = threadIdx.x & 63;
    if (lane == 0) { s_lp[wid] = lp; s_ln[wid] = ln; s_cp[wid] = cp; s_cn[wid] = cn; }
    __syncthreads();
    if (threadIdx.x == 0) {
        float blp = 0.f, bln = 0.f;
        unsigned bcp = 0u, bcn = 0u;
        for (int w = 0; w < 4; ++w) { blp += s_lp[w]; bln += s_ln[w]; bcp += s_cp[w]; bcn += s_cn[w]; }
        atomicAdd(&ws->loss_pos, (double)blp);
        atomicAdd(&ws->sum_neg, (double)bln);
        atomicAdd(&ws->cnt_pos, bcp);
        atomicAdd(&ws->cnt_neg, bcn);
    }
}

__global__ __launch_bounds__(256) void k_finalize(const float* __restrict__ pred,
                                                  const int* __restrict__ gt,
                                                  const int* __restrict__ ratio,
                                                  const WsHeader* __restrict__ ws,
                                                  float* __restrict__ out) {
    const unsigned cp = ws->cnt_pos, cn = ws->cnt_neg;
    const float rf = (float)ratio[0];
    long long nneg_ll = (long long)(rf * (float)cp);   // trunc toward zero, as reference
    if (nneg_ll < 0) nneg_ll = 0;
    const unsigned nneg = (unsigned)((nneg_ll < (long long)cn) ? nneg_ll : (long long)cn);
    const double denom = (double)cp + (double)nneg;

    if (nneg >= cn) {                 // common case for this input distribution
        if (threadIdx.x == 0)
            out[0] = (denom > 0.0) ? (float)((ws->loss_pos + ws->sum_neg) / denom) : 0.0f;
        return;
    }
    if (nneg == 0) {
        if (threadIdx.x == 0)
            out[0] = (denom > 0.0) ? (float)(ws->loss_pos / denom) : 0.0f;
        return;
    }

    // ---- exact top-k fallback: radix select k-th largest CE among negatives ----
    __shared__ unsigned s_hist[256];
    __shared__ unsigned s_prefix, s_k;
    if (threadIdx.x == 0) { s_prefix = 0u; s_k = nneg; }
    __syncthreads();
    for (int round = 0; round < 4; ++round) {
        const int shift = 24 - 8 * round;
        for (int i = threadIdx.x; i < 256; i += blockDim.x) s_hist[i] = 0u;
        __syncthreads();
        const unsigned prefix = s_prefix;
        const unsigned pmask = (round == 0) ? 0u : (0xFFFFFFFFu << (shift + 8));
        for (int p = threadIdx.x; p < NPIX_; p += blockDim.x) {
            const int t = gt[p];
            if ((unsigned)(t - 1) <= 2u) continue;    // positive — skip
            const unsigned key = f2ord(pixel_ce(pred, p, t));
            if ((key & pmask) == prefix)
                atomicAdd(&s_hist[(key >> shift) & 255u], 1u);
        }
        __syncthreads();
        if (threadIdx.x == 0) {
            const unsigned kk = s_k;
            unsigned cum = 0u;
            for (int i = 255; i >= 0; --i) {
                const unsigned h = s_hist[i];
                if (cum + h >= kk) {
                    s_k = kk - cum;
                    s_prefix = prefix | ((unsigned)i << shift);
                    break;
                }
                cum += h;
            }
        }
        __syncthreads();
    }
    const unsigned Tkey = s_prefix;       // exact key of the k-th largest value
    const float Tval = ord2f(Tkey);
    double sgt = 0.0;
    unsigned cgt = 0u;
    for (int p = threadIdx.x; p < NPIX_; p += blockDim.x) {
        const int t = gt[p];
        if ((unsigned)(t - 1) <= 2u) continue;
        const float ce = pixel_ce(pred, p, t);
        if (f2ord(ce) > Tkey) { sgt += (double)ce; ++cgt; }
    }
#pragma unroll
    for (int off = 32; off > 0; off >>= 1) {
        sgt += __shfl_down(sgt, off);
        cgt += __shfl_down(cgt, off);
    }
    __shared__ double s_s[4];
    __shared__ unsigned s_c[4];
    const int wid = threadIdx.x >> 6;
    const int lane = threadIdx.x & 63;
    if (lane == 0) { s_s[wid] = sgt; s_c[wid] = cgt; }
    __syncthreads();
    if (threadIdx.x == 0) {
        double S = 0.0;
        unsigned Cg = 0u;
        for (int w = 0; w < 4; ++w) { S += s_s[w]; Cg += s_c[w]; }
        const double loss_neg = S + (double)(nneg - Cg) * (double)Tval;  // ties at T
        out[0] = (float)((ws->loss_pos + loss_neg) / denom);
    }
}

extern "C" void kernel_launch(void* const* d_in, const int* in_sizes, int n_in,
                              void* d_out, int out_size, void* d_ws, size_t ws_size,
                              hipStream_t stream) {
    const float* pred = (const float*)d_in[0];
    const int* gt = (const int*)d_in[1];
    const int* ratio = (const int*)d_in[2];
    float* out = (float*)d_out;
    WsHeader* ws = (WsHeader*)d_ws;

    hipMemsetAsync(d_ws, 0, sizeof(WsHeader), stream);  // accumulators zeroed each call
    k_ce_pass<<<2048, 256, 0, stream>>>(pred, gt, ws);
    k_finalize<<<1, 256, 0, stream>>>(pred, gt, ratio, ws, out);
}

// Round 2
// 101.503 us; speedup vs baseline: 1.2509x; 1.2509x over previous
//
#include <hip/hip_runtime.h>

// OhemCELoss on MI355X (gfx950).
// pred [B=16, C=5, H=768, W=768] f32; gt [B,H,W] int32; ratio scalar int.
// R1 -> R2: latency-bound fix. Previous build allocated only 24 VGPRs ->
// serialized the 5 plane loads. Now: 8 pixels/thread/iter (12 independent
// vector loads up-front), launch_bounds(256,4) for a ~128-VGPR budget,
// exact 3-iteration grid, fast __expf/__logf.

static constexpr int B_ = 16, C_ = 5, H_ = 768, W_ = 768;
static constexpr int HW_ = H_ * W_;          // 589824 (divisible by 8)
static constexpr int NPIX_ = B_ * HW_;       // 9,437,184
static constexpr int NOCT_ = NPIX_ / 8;      // 1,179,648

struct WsHeader {
    double loss_pos;   // sum CE over positives
    double sum_neg;    // sum CE over ALL negatives
    unsigned cnt_pos;
    unsigned cnt_neg;
    unsigned pad[2];
};

__device__ __forceinline__ unsigned f2ord(float f) {
    unsigned u = __float_as_uint(f);
    return (u & 0x80000000u) ? ~u : (u | 0x80000000u);
}
__device__ __forceinline__ float ord2f(unsigned o) {
    unsigned v = (o & 0x80000000u) ? (o & 0x7FFFFFFFu) : ~o;
    return __uint_as_float(v);
}

__device__ __forceinline__ float pixel_ce_precise(const float* __restrict__ pred, int p, int t) {
    const int b = p / HW_;
    const int hw = p - b * HW_;
    const float* base = pred + (size_t)b * (C_ * HW_) + hw;
    const float x0 = base[0], x1 = base[HW_], x2 = base[2 * HW_],
                x3 = base[3 * HW_], x4 = base[4 * HW_];
    const float m = fmaxf(fmaxf(fmaxf(x0, x1), fmaxf(x2, x3)), x4);
    const float lse = m + logf(expf(x0 - m) + expf(x1 - m) + expf(x2 - m) +
                               expf(x3 - m) + expf(x4 - m));
    const float xt = (t == 0) ? x0 : (t == 1) ? x1 : (t == 2) ? x2 : (t == 3) ? x3 : x4;
    return lse - xt;
}

__global__ __launch_bounds__(256, 4) void k_ce_pass(const float* __restrict__ pred,
                                                    const int* __restrict__ gt,
                                                    WsHeader* __restrict__ ws) {
    float lp = 0.f, ln = 0.f;
    unsigned cp = 0u, cn = 0u;
    const int stride = gridDim.x * blockDim.x;

    for (int o = blockIdx.x * blockDim.x + threadIdx.x; o < NOCT_; o += stride) {
        const int p = o << 3;              // 8 consecutive pixels, same b (HW_%8==0)
        const int b = p / HW_;
        const int hw = p - b * HW_;
        const float* base = pred + (size_t)b * (C_ * HW_) + hw;

        // Issue all 12 loads up-front; keep them in named registers.
        const float4 v0a = *reinterpret_cast<const float4*>(base);
        const float4 v0b = *reinterpret_cast<const float4*>(base + 4);
        const float4 v1a = *reinterpret_cast<const float4*>(base + HW_);
        const float4 v1b = *reinterpret_cast<const float4*>(base + HW_ + 4);
        const float4 v2a = *reinterpret_cast<const float4*>(base + 2 * HW_);
        const float4 v2b = *reinterpret_cast<const float4*>(base + 2 * HW_ + 4);
        const float4 v3a = *reinterpret_cast<const float4*>(base + 3 * HW_);
        const float4 v3b = *reinterpret_cast<const float4*>(base + 3 * HW_ + 4);
        const float4 v4a = *reinterpret_cast<const float4*>(base + 4 * HW_);
        const float4 v4b = *reinterpret_cast<const float4*>(base + 4 * HW_ + 4);
        const int4 ta = *reinterpret_cast<const int4*>(gt + p);
        const int4 tb = *reinterpret_cast<const int4*>(gt + p + 4);

        auto do_pix = [&](float x0, float x1, float x2, float x3, float x4, int t) {
            const float m = fmaxf(fmaxf(fmaxf(x0, x1), fmaxf(x2, x3)), x4);
            const float se = __expf(x0 - m) + __expf(x1 - m) + __expf(x2 - m) +
                             __expf(x3 - m) + __expf(x4 - m);
            const float xt = (t == 0) ? x0 : (t == 1) ? x1 : (t == 2) ? x2
                           : (t == 3) ? x3 : x4;
            const float ce = m + __logf(se) - xt;
            if ((unsigned)(t - 1) <= 2u) { lp += ce; ++cp; }
            else                          { ln += ce; ++cn; }
        };

        do_pix(v0a.x, v1a.x, v2a.x, v3a.x, v4a.x, ta.x);
        do_pix(v0a.y, v1a.y, v2a.y, v3a.y, v4a.y, ta.y);
        do_pix(v0a.z, v1a.z, v2a.z, v3a.z, v4a.z, ta.z);
        do_pix(v0a.w, v1a.w, v2a.w, v3a.w, v4a.w, ta.w);
        do_pix(v0b.x, v1b.x, v2b.x, v3b.x, v4b.x, tb.x);
        do_pix(v0b.y, v1b.y, v2b.y, v3b.y, v4b.y, tb.y);
        do_pix(v0b.z, v1b.z, v2b.z, v3b.z, v4b.z, tb.z);
        do_pix(v0b.w, v1b.w, v2b.w, v3b.w, v4b.w, tb.w);
    }

    // wave64 reduce
#pragma unroll
    for (int off = 32; off > 0; off >>= 1) {
        lp += __shfl_down(lp, off);
        ln += __shfl_down(ln, off);
        cp += __shfl_down(cp, off);
        cn += __shfl_down(cn, off);
    }
    __shared__ float s_lp[4], s_ln[4];
    __shared__ unsigned s_cp[4], s_cn[4];
    const int wid = threadIdx.x >> 6;
    const int lane = threadIdx.x & 63;
    if (lane == 0) { s_lp[wid] = lp; s_ln[wid] = ln; s_cp[wid] = cp; s_cn[wid] = cn; }
    __syncthreads();
    if (threadIdx.x == 0) {
        float blp = 0.f, bln = 0.f;
        unsigned bcp = 0u, bcn = 0u;
        for (int w = 0; w < 4; ++w) { blp += s_lp[w]; bln += s_ln[w]; bcp += s_cp[w]; bcn += s_cn[w]; }
        atomicAdd(&ws->loss_pos, (double)blp);
        atomicAdd(&ws->sum_neg, (double)bln);
        atomicAdd(&ws->cnt_pos, bcp);
        atomicAdd(&ws->cnt_neg, bcn);
    }
}

__global__ __launch_bounds__(256) void k_finalize(const float* __restrict__ pred,
                                                  const int* __restrict__ gt,
                                                  const int* __restrict__ ratio,
                                                  const WsHeader* __restrict__ ws,
                                                  float* __restrict__ out) {
    const unsigned cp = ws->cnt_pos, cn = ws->cnt_neg;
    const float rf = (float)ratio[0];
    long long nneg_ll = (long long)(rf * (float)cp);   // trunc toward zero, as reference
    if (nneg_ll < 0) nneg_ll = 0;
    const unsigned nneg = (unsigned)((nneg_ll < (long long)cn) ? nneg_ll : (long long)cn);
    const double denom = (double)cp + (double)nneg;

    if (nneg >= cn) {                 // common case for this input distribution
        if (threadIdx.x == 0)
            out[0] = (denom > 0.0) ? (float)((ws->loss_pos + ws->sum_neg) / denom) : 0.0f;
        return;
    }
    if (nneg == 0) {
        if (threadIdx.x == 0)
            out[0] = (denom > 0.0) ? (float)(ws->loss_pos / denom) : 0.0f;
        return;
    }

    // ---- exact top-k fallback: radix select k-th largest CE among negatives ----
    __shared__ unsigned s_hist[256];
    __shared__ unsigned s_prefix, s_k;
    if (threadIdx.x == 0) { s_prefix = 0u; s_k = nneg; }
    __syncthreads();
    for (int round = 0; round < 4; ++round) {
        const int shift = 24 - 8 * round;
        for (int i = threadIdx.x; i < 256; i += blockDim.x) s_hist[i] = 0u;
        __syncthreads();
        const unsigned prefix = s_prefix;
        const unsigned pmask = (round == 0) ? 0u : (0xFFFFFFFFu << (shift + 8));
        for (int p = threadIdx.x; p < NPIX_; p += blockDim.x) {
            const int t = gt[p];
            if ((unsigned)(t - 1) <= 2u) continue;    // positive — skip
            const unsigned key = f2ord(pixel_ce_precise(pred, p, t));
            if ((key & pmask) == prefix)
                atomicAdd(&s_hist[(key >> shift) & 255u], 1u);
        }
        __syncthreads();
        if (threadIdx.x == 0) {
            const unsigned kk = s_k;
            unsigned cum = 0u;
            for (int i = 255; i >= 0; --i) {
                const unsigned h = s_hist[i];
                if (cum + h >= kk) {
                    s_k = kk - cum;
                    s_prefix = prefix | ((unsigned)i << shift);
                    break;
                }
                cum += h;
            }
        }
        __syncthreads();
    }
    const unsigned Tkey = s_prefix;       // exact key of the k-th largest value
    const float Tval = ord2f(Tkey);
    double sgt = 0.0;
    unsigned cgt = 0u;
    for (int p = threadIdx.x; p < NPIX_; p += blockDim.x) {
        const int t = gt[p];
        if ((unsigned)(t - 1) <= 2u) continue;
        const float ce = pixel_ce_precise(pred, p, t);
        if (f2ord(ce) > Tkey) { sgt += (double)ce; ++cgt; }
    }
#pragma unroll
    for (int off = 32; off > 0; off >>= 1) {
        sgt += __shfl_down(sgt, off);
        cgt += __shfl_down(cgt, off);
    }
    __shared__ double s_s[4];
    __shared__ unsigned s_c[4];
    const int wid = threadIdx.x >> 6;
    const int lane = threadIdx.x & 63;
    if (lane == 0) { s_s[wid] = sgt; s_c[wid] = cgt; }
    __syncthreads();
    if (threadIdx.x == 0) {
        double S = 0.0;
        unsigned Cg = 0u;
        for (int w = 0; w < 4; ++w) { S += s_s[w]; Cg += s_c[w]; }
        const double loss_neg = S + (double)(nneg - Cg) * (double)Tval;  // ties at T
        out[0] = (float)((ws->loss_pos + loss_neg) / denom);
    }
}

extern "C" void kernel_launch(void* const* d_in, const int* in_sizes, int n_in,
                              void* d_out, int out_size, void* d_ws, size_t ws_size,
                              hipStream_t stream) {
    const float* pred = (const float*)d_in[0];
    const int* gt = (const int*)d_in[1];
    const int* ratio = (const int*)d_in[2];
    float* out = (float*)d_out;
    WsHeader* ws = (WsHeader*)d_ws;

    hipMemsetAsync(d_ws, 0, sizeof(WsHeader), stream);  // accumulators zeroed each call
    // 1536 blocks x 256 threads -> 393216 threads; NOCT_/threads = 3 exact iters.
    k_ce_pass<<<1536, 256, 0, stream>>>(pred, gt, ws);
    k_finalize<<<1, 256, 0, stream>>>(pred, gt, ratio, ws, out);
}

// Round 3
// 49.746 us; speedup vs baseline: 2.5523x; 2.0404x over previous
//
#include <hip/hip_runtime.h>

// OhemCELoss on MI355X (gfx950).
// pred [B=16, C=5, H=768, W=768] f32; gt [B,H,W] int32; ratio scalar int.
// R2 -> R3: the bottleneck was 4 same-cache-line atomics per block (f64 FADD
// serialization at L2: ~12 ns x 6144 atomics ~= 75 us). Now: zero atomics.
// Each block writes partials to a private 16B slot; k_finalize reduces slots.
// Main pass: one-shot grid (9216 blocks x 256 thr = NQUAD exactly), 4 pixels
// per thread, lane-contiguous float4 loads, no-max log-sum-exp (|x|<~6).

static constexpr int B_ = 16, C_ = 5, H_ = 768, W_ = 768;
static constexpr int HW_ = H_ * W_;            // 589824
static constexpr int NPIX_ = B_ * HW_;         // 9,437,184
static constexpr int NQUAD_ = NPIX_ / 4;       // 2,359,296
static constexpr int NBLK_ = NQUAD_ / 256;     // 9216 blocks
static constexpr int BLKS_PER_B_ = HW_ / 1024; // 576 blocks per batch image

struct Slot { float lp; float lall; unsigned cp; unsigned pad; };  // 16 B

__device__ __forceinline__ unsigned f2ord(float f) {
    unsigned u = __float_as_uint(f);
    return (u & 0x80000000u) ? ~u : (u | 0x80000000u);
}
__device__ __forceinline__ float ord2f(unsigned o) {
    unsigned v = (o & 0x80000000u) ? (o & 0x7FFFFFFFu) : ~o;
    return __uint_as_float(v);
}

// Precise CE (max-subtracted, libm) — used only by the never-taken fallback.
__device__ __forceinline__ float pixel_ce_precise(const float* __restrict__ pred, int p, int t) {
    const int b = p / HW_;
    const int hw = p - b * HW_;
    const float* base = pred + (size_t)b * (C_ * HW_) + hw;
    const float x0 = base[0], x1 = base[HW_], x2 = base[2 * HW_],
                x3 = base[3 * HW_], x4 = base[4 * HW_];
    const float m = fmaxf(fmaxf(fmaxf(x0, x1), fmaxf(x2, x3)), x4);
    const float lse = m + logf(expf(x0 - m) + expf(x1 - m) + expf(x2 - m) +
                               expf(x3 - m) + expf(x4 - m));
    const float xt = (t == 0) ? x0 : (t == 1) ? x1 : (t == 2) ? x2 : (t == 3) ? x3 : x4;
    return lse - xt;
}

__global__ __launch_bounds__(256, 8) void k_ce_pass(const float* __restrict__ pred,
                                                    const int* __restrict__ gt,
                                                    Slot* __restrict__ slots) {
    const int bb = blockIdx.x / BLKS_PER_B_;                      // uniform per block
    const int hw = (blockIdx.x - bb * BLKS_PER_B_) * 1024 + threadIdx.x * 4;
    const float* base = pred + (size_t)bb * (C_ * HW_) + hw;

    // 6 independent vector loads, lane-contiguous (1 KB/wave per instruction).
    const float4 v0 = *reinterpret_cast<const float4*>(base);
    const float4 v1 = *reinterpret_cast<const float4*>(base + HW_);
    const float4 v2 = *reinterpret_cast<const float4*>(base + 2 * HW_);
    const float4 v3 = *reinterpret_cast<const float4*>(base + 3 * HW_);
    const float4 v4 = *reinterpret_cast<const float4*>(base + 4 * HW_);
    const int4 t4 = *reinterpret_cast<const int4*>(gt + bb * HW_ + hw);

    float lp = 0.f, lall = 0.f;
    unsigned cp = 0u;

    auto pix = [&](float x0, float x1, float x2, float x3, float x4, int t) {
        const float se = __expf(x0) + __expf(x1) + __expf(x2) + __expf(x3) + __expf(x4);
        const float xt = (t == 0) ? x0 : (t == 1) ? x1 : (t == 2) ? x2 : (t == 3) ? x3 : x4;
        const float ce = __logf(se) - xt;
        const bool pos = ((unsigned)(t - 1) <= 2u);
        lall += ce;
        lp += pos ? ce : 0.0f;
        cp += pos ? 1u : 0u;
    };
    pix(v0.x, v1.x, v2.x, v3.x, v4.x, t4.x);
    pix(v0.y, v1.y, v2.y, v3.y, v4.y, t4.y);
    pix(v0.z, v1.z, v2.z, v3.z, v4.z, t4.z);
    pix(v0.w, v1.w, v2.w, v3.w, v4.w, t4.w);

    // wave64 reduce
#pragma unroll
    for (int off = 32; off > 0; off >>= 1) {
        lp += __shfl_down(lp, off);
        lall += __shfl_down(lall, off);
        cp += __shfl_down(cp, off);
    }
    __shared__ float s_lp[4], s_la[4];
    __shared__ unsigned s_cp[4];
    const int wid = threadIdx.x >> 6;
    const int lane = threadIdx.x & 63;
    if (lane == 0) { s_lp[wid] = lp; s_la[wid] = lall; s_cp[wid] = cp; }
    __syncthreads();
    if (threadIdx.x == 0) {
        Slot s;
        s.lp = s_lp[0] + s_lp[1] + s_lp[2] + s_lp[3];
        s.lall = s_la[0] + s_la[1] + s_la[2] + s_la[3];
        s.cp = s_cp[0] + s_cp[1] + s_cp[2] + s_cp[3];
        s.pad = 0u;
        slots[blockIdx.x] = s;       // private 16B slot — no atomics anywhere
    }
}

__global__ __launch_bounds__(256) void k_finalize(const float* __restrict__ pred,
                                                  const int* __restrict__ gt,
                                                  const int* __restrict__ ratio,
                                                  const Slot* __restrict__ slots,
                                                  float* __restrict__ out) {
    // ---- reduce the 9216 slots ----
    double dlp = 0.0, dla = 0.0;
    unsigned c = 0u;
    for (int i = threadIdx.x; i < NBLK_; i += 256) {
        const Slot s = slots[i];
        dlp += (double)s.lp;
        dla += (double)s.lall;
        c += s.cp;
    }
#pragma unroll
    for (int off = 32; off > 0; off >>= 1) {
        dlp += __shfl_down(dlp, off);
        dla += __shfl_down(dla, off);
        c += __shfl_down(c, off);
    }
    __shared__ double sdp[4], sda[4];
    __shared__ unsigned sc[4];
    __shared__ double t_lp, t_la;
    __shared__ unsigned t_cp;
    {
        const int wid = threadIdx.x >> 6;
        const int lane = threadIdx.x & 63;
        if (lane == 0) { sdp[wid] = dlp; sda[wid] = dla; sc[wid] = c; }
        __syncthreads();
        if (threadIdx.x == 0) {
            t_lp = sdp[0] + sdp[1] + sdp[2] + sdp[3];
            t_la = sda[0] + sda[1] + sda[2] + sda[3];
            t_cp = sc[0] + sc[1] + sc[2] + sc[3];
        }
        __syncthreads();
    }
    const double loss_pos = t_lp;
    const double sum_neg = t_la - t_lp;        // sum CE over ALL negatives
    const unsigned cp = t_cp;
    const unsigned cn = (unsigned)NPIX_ - cp;

    const float rf = (float)ratio[0];
    long long nneg_ll = (long long)(rf * (float)cp);   // f32 mul + trunc, as reference
    if (nneg_ll < 0) nneg_ll = 0;
    const unsigned nneg = (unsigned)((nneg_ll < (long long)cn) ? nneg_ll : (long long)cn);
    const double denom = (double)cp + (double)nneg;

    if (nneg >= cn) {                 // common case for this input distribution
        if (threadIdx.x == 0)
            out[0] = (denom > 0.0) ? (float)((loss_pos + sum_neg) / denom) : 0.0f;
        return;
    }
    if (nneg == 0) {
        if (threadIdx.x == 0)
            out[0] = (denom > 0.0) ? (float)(loss_pos / denom) : 0.0f;
        return;
    }

    // ---- exact top-k fallback: radix select k-th largest CE among negatives ----
    __shared__ unsigned s_hist[256];
    __shared__ unsigned s_prefix, s_k;
    if (threadIdx.x == 0) { s_prefix = 0u; s_k = nneg; }
    __syncthreads();
    for (int round = 0; round < 4; ++round) {
        const int shift = 24 - 8 * round;
        for (int i = threadIdx.x; i < 256; i += blockDim.x) s_hist[i] = 0u;
        __syncthreads();
        const unsigned prefix = s_prefix;
        const unsigned pmask = (round == 0) ? 0u : (0xFFFFFFFFu << (shift + 8));
        for (int p = threadIdx.x; p < NPIX_; p += blockDim.x) {
            const int t = gt[p];
            if ((unsigned)(t - 1) <= 2u) continue;    // positive — skip
            const unsigned key = f2ord(pixel_ce_precise(pred, p, t));
            if ((key & pmask) == prefix)
                atomicAdd(&s_hist[(key >> shift) & 255u], 1u);
        }
        __syncthreads();
        if (threadIdx.x == 0) {
            const unsigned kk = s_k;
            unsigned cum = 0u;
            for (int i = 255; i >= 0; --i) {
                const unsigned h = s_hist[i];
                if (cum + h >= kk) {
                    s_k = kk - cum;
                    s_prefix = prefix | ((unsigned)i << shift);
                    break;
                }
                cum += h;
            }
        }
        __syncthreads();
    }
    const unsigned Tkey = s_prefix;       // exact key of the k-th largest value
    const float Tval = ord2f(Tkey);
    double sgt = 0.0;
    unsigned cgt = 0u;
    for (int p = threadIdx.x; p < NPIX_; p += blockDim.x) {
        const int t = gt[p];
        if ((unsigned)(t - 1) <= 2u) continue;
        const float ce = pixel_ce_precise(pred, p, t);
        if (f2ord(ce) > Tkey) { sgt += (double)ce; ++cgt; }
    }
#pragma unroll
    for (int off = 32; off > 0; off >>= 1) {
        sgt += __shfl_down(sgt, off);
        cgt += __shfl_down(cgt, off);
    }
    __shared__ double s_s[4];
    __shared__ unsigned s_c[4];
    const int wid = threadIdx.x >> 6;
    const int lane = threadIdx.x & 63;
    if (lane == 0) { s_s[wid] = sgt; s_c[wid] = cgt; }
    __syncthreads();
    if (threadIdx.x == 0) {
        double S = 0.0;
        unsigned Cg = 0u;
        for (int w = 0; w < 4; ++w) { S += s_s[w]; Cg += s_c[w]; }
        const double loss_neg = S + (double)(nneg - Cg) * (double)Tval;  // ties at T
        out[0] = (float)((loss_pos + loss_neg) / denom);
    }
}

extern "C" void kernel_launch(void* const* d_in, const int* in_sizes, int n_in,
                              void* d_out, int out_size, void* d_ws, size_t ws_size,
                              hipStream_t stream) {
    const float* pred = (const float*)d_in[0];
    const int* gt = (const int*)d_in[1];
    const int* ratio = (const int*)d_in[2];
    float* out = (float*)d_out;
    Slot* slots = (Slot*)d_ws;

    k_ce_pass<<<NBLK_, 256, 0, stream>>>(pred, gt, slots);   // writes every slot
    k_finalize<<<1, 256, 0, stream>>>(pred, gt, ratio, slots, out);
}

// Round 4
// 43.307 us; speedup vs baseline: 2.9317x; 1.1487x over previous
//
#include <hip/hip_runtime.h>

// OhemCELoss on MI355X (gfx950).
// pred [B=16, C=5, H=768, W=768] f32; gt [B,H,W] int32; ratio scalar int.
// R3 -> R4: latency/issue-bound fix. 16 px/thread (4 coalesced 1KB chunks,
// 24 independent vector loads up-front), 2304 blocks (4x fewer workgroups),
// slots 9216 -> 2304 so finalize's strided slot reduce is 9 iterations.
// Zero atomics (R3's win); no workspace zeroing needed (every slot written).

static constexpr int B_ = 16, C_ = 5, H_ = 768, W_ = 768;
static constexpr int HW_ = H_ * W_;            // 589824
static constexpr int NPIX_ = B_ * HW_;         // 9,437,184
static constexpr int PIX_PER_BLK_ = 4096;      // 256 thr x 16 px
static constexpr int NBLK_ = NPIX_ / PIX_PER_BLK_;      // 2304
static constexpr int BLKS_PER_B_ = HW_ / PIX_PER_BLK_;  // 144

struct Slot { float lp; float lall; unsigned cp; unsigned pad; };  // 16 B

__device__ __forceinline__ unsigned f2ord(float f) {
    unsigned u = __float_as_uint(f);
    return (u & 0x80000000u) ? ~u : (u | 0x80000000u);
}
__device__ __forceinline__ float ord2f(unsigned o) {
    unsigned v = (o & 0x80000000u) ? (o & 0x7FFFFFFFu) : ~o;
    return __uint_as_float(v);
}

// Precise CE (max-subtracted, libm) — used only by the never-taken fallback.
__device__ __forceinline__ float pixel_ce_precise(const float* __restrict__ pred, int p, int t) {
    const int b = p / HW_;
    const int hw = p - b * HW_;
    const float* base = pred + (size_t)b * (C_ * HW_) + hw;
    const float x0 = base[0], x1 = base[HW_], x2 = base[2 * HW_],
                x3 = base[3 * HW_], x4 = base[4 * HW_];
    const float m = fmaxf(fmaxf(fmaxf(x0, x1), fmaxf(x2, x3)), x4);
    const float lse = m + logf(expf(x0 - m) + expf(x1 - m) + expf(x2 - m) +
                               expf(x3 - m) + expf(x4 - m));
    const float xt = (t == 0) ? x0 : (t == 1) ? x1 : (t == 2) ? x2 : (t == 3) ? x3 : x4;
    return lse - xt;
}

__global__ __launch_bounds__(256, 4) void k_ce_pass(const float* __restrict__ pred,
                                                    const int* __restrict__ gt,
                                                    Slot* __restrict__ slots) {
    const int bb = blockIdx.x / BLKS_PER_B_;                      // uniform per block
    const int hw0 = (blockIdx.x - bb * BLKS_PER_B_) * PIX_PER_BLK_ + threadIdx.x * 4;
    const float* base = pred + (size_t)bb * (C_ * HW_) + hw0;
    const int* gbase = gt + bb * HW_ + hw0;

    // 4 chunks of 1024 px, each lane-contiguous; 24 independent loads total.
    float4 v[4][5];
    int4 t4[4];
#pragma unroll
    for (int c = 0; c < 4; ++c) {
        const float* cb = base + c * 1024;
#pragma unroll
        for (int pl = 0; pl < 5; ++pl)
            v[c][pl] = *reinterpret_cast<const float4*>(cb + pl * HW_);
        t4[c] = *reinterpret_cast<const int4*>(gbase + c * 1024);
    }

    float lp = 0.f, lall = 0.f;
    unsigned cp = 0u;

    auto pix = [&](float x0, float x1, float x2, float x3, float x4, int t) {
        const float se = __expf(x0) + __expf(x1) + __expf(x2) + __expf(x3) + __expf(x4);
        const float xt = (t == 0) ? x0 : (t == 1) ? x1 : (t == 2) ? x2 : (t == 3) ? x3 : x4;
        const float ce = __logf(se) - xt;
        const bool pos = ((unsigned)(t - 1) <= 2u);
        lall += ce;
        lp += pos ? ce : 0.0f;
        cp += pos ? 1u : 0u;
    };
#pragma unroll
    for (int c = 0; c < 4; ++c) {
        pix(v[c][0].x, v[c][1].x, v[c][2].x, v[c][3].x, v[c][4].x, t4[c].x);
        pix(v[c][0].y, v[c][1].y, v[c][2].y, v[c][3].y, v[c][4].y, t4[c].y);
        pix(v[c][0].z, v[c][1].z, v[c][2].z, v[c][3].z, v[c][4].z, t4[c].z);
        pix(v[c][0].w, v[c][1].w, v[c][2].w, v[c][3].w, v[c][4].w, t4[c].w);
    }

    // wave64 reduce
#pragma unroll
    for (int off = 32; off > 0; off >>= 1) {
        lp += __shfl_down(lp, off);
        lall += __shfl_down(lall, off);
        cp += __shfl_down(cp, off);
    }
    __shared__ float s_lp[4], s_la[4];
    __shared__ unsigned s_cp[4];
    const int wid = threadIdx.x >> 6;
    const int lane = threadIdx.x & 63;
    if (lane == 0) { s_lp[wid] = lp; s_la[wid] = lall; s_cp[wid] = cp; }
    __syncthreads();
    if (threadIdx.x == 0) {
        Slot s;
        s.lp = s_lp[0] + s_lp[1] + s_lp[2] + s_lp[3];
        s.lall = s_la[0] + s_la[1] + s_la[2] + s_la[3];
        s.cp = s_cp[0] + s_cp[1] + s_cp[2] + s_cp[3];
        s.pad = 0u;
        slots[blockIdx.x] = s;       // private 16B slot — no atomics anywhere
    }
}

__global__ __launch_bounds__(256) void k_finalize(const float* __restrict__ pred,
                                                  const int* __restrict__ gt,
                                                  const int* __restrict__ ratio,
                                                  const Slot* __restrict__ slots,
                                                  float* __restrict__ out) {
    // ---- reduce the 2304 slots (9 strided iterations) ----
    double dlp = 0.0, dla = 0.0;
    unsigned c = 0u;
#pragma unroll
    for (int i = 0; i < NBLK_ / 256; ++i) {
        const Slot s = slots[i * 256 + threadIdx.x];
        dlp += (double)s.lp;
        dla += (double)s.lall;
        c += s.cp;
    }
#pragma unroll
    for (int off = 32; off > 0; off >>= 1) {
        dlp += __shfl_down(dlp, off);
        dla += __shfl_down(dla, off);
        c += __shfl_down(c, off);
    }
    __shared__ double sdp[4], sda[4];
    __shared__ unsigned sc[4];
    __shared__ double t_lp, t_la;
    __shared__ unsigned t_cp;
    {
        const int wid = threadIdx.x >> 6;
        const int lane = threadIdx.x & 63;
        if (lane == 0) { sdp[wid] = dlp; sda[wid] = dla; sc[wid] = c; }
        __syncthreads();
        if (threadIdx.x == 0) {
            t_lp = sdp[0] + sdp[1] + sdp[2] + sdp[3];
            t_la = sda[0] + sda[1] + sda[2] + sda[3];
            t_cp = sc[0] + sc[1] + sc[2] + sc[3];
        }
        __syncthreads();
    }
    const double loss_pos = t_lp;
    const double sum_neg = t_la - t_lp;        // sum CE over ALL negatives
    const unsigned cp = t_cp;
    const unsigned cn = (unsigned)NPIX_ - cp;

    const float rf = (float)ratio[0];
    long long nneg_ll = (long long)(rf * (float)cp);   // f32 mul + trunc, as reference
    if (nneg_ll < 0) nneg_ll = 0;
    const unsigned nneg = (unsigned)((nneg_ll < (long long)cn) ? nneg_ll : (long long)cn);
    const double denom = (double)cp + (double)nneg;

    if (nneg >= cn) {                 // common case for this input distribution
        if (threadIdx.x == 0)
            out[0] = (denom > 0.0) ? (float)((loss_pos + sum_neg) / denom) : 0.0f;
        return;
    }
    if (nneg == 0) {
        if (threadIdx.x == 0)
            out[0] = (denom > 0.0) ? (float)(loss_pos / denom) : 0.0f;
        return;
    }

    // ---- exact top-k fallback: radix select k-th largest CE among negatives ----
    __shared__ unsigned s_hist[256];
    __shared__ unsigned s_prefix, s_k;
    if (threadIdx.x == 0) { s_prefix = 0u; s_k = nneg; }
    __syncthreads();
    for (int round = 0; round < 4; ++round) {
        const int shift = 24 - 8 * round;
        for (int i = threadIdx.x; i < 256; i += blockDim.x) s_hist[i] = 0u;
        __syncthreads();
        const unsigned prefix = s_prefix;
        const unsigned pmask = (round == 0) ? 0u : (0xFFFFFFFFu << (shift + 8));
        for (int p = threadIdx.x; p < NPIX_; p += blockDim.x) {
            const int t = gt[p];
            if ((unsigned)(t - 1) <= 2u) continue;    // positive — skip
            const unsigned key = f2ord(pixel_ce_precise(pred, p, t));
            if ((key & pmask) == prefix)
                atomicAdd(&s_hist[(key >> shift) & 255u], 1u);
        }
        __syncthreads();
        if (threadIdx.x == 0) {
            const unsigned kk = s_k;
            unsigned cum = 0u;
            for (int i = 255; i >= 0; --i) {
                const unsigned h = s_hist[i];
                if (cum + h >= kk) {
                    s_k = kk - cum;
                    s_prefix = prefix | ((unsigned)i << shift);
                    break;
                }
                cum += h;
            }
        }
        __syncthreads();
    }
    const unsigned Tkey = s_prefix;       // exact key of the k-th largest value
    const float Tval = ord2f(Tkey);
    double sgt = 0.0;
    unsigned cgt = 0u;
    for (int p = threadIdx.x; p < NPIX_; p += blockDim.x) {
        const int t = gt[p];
        if ((unsigned)(t - 1) <= 2u) continue;
        const float ce = pixel_ce_precise(pred, p, t);
        if (f2ord(ce) > Tkey) { sgt += (double)ce; ++cgt; }
    }
#pragma unroll
    for (int off = 32; off > 0; off >>= 1) {
        sgt += __shfl_down(sgt, off);
        cgt += __shfl_down(cgt, off);
    }
    __shared__ double s_s[4];
    __shared__ unsigned s_c[4];
    const int wid = threadIdx.x >> 6;
    const int lane = threadIdx.x & 63;
    if (lane == 0) { s_s[wid] = sgt; s_c[wid] = cgt; }
    __syncthreads();
    if (threadIdx.x == 0) {
        double S = 0.0;
        unsigned Cg = 0u;
        for (int w = 0; w < 4; ++w) { S += s_s[w]; Cg += s_c[w]; }
        const double loss_neg = S + (double)(nneg - Cg) * (double)Tval;  // ties at T
        out[0] = (float)((loss_pos + loss_neg) / denom);
    }
}

extern "C" void kernel_launch(void* const* d_in, const int* in_sizes, int n_in,
                              void* d_out, int out_size, void* d_ws, size_t ws_size,
                              hipStream_t stream) {
    const float* pred = (const float*)d_in[0];
    const int* gt = (const int*)d_in[1];
    const int* ratio = (const int*)d_in[2];
    float* out = (float*)d_out;
    Slot* slots = (Slot*)d_ws;

    k_ce_pass<<<NBLK_, 256, 0, stream>>>(pred, gt, slots);   // writes every slot
    k_finalize<<<1, 256, 0, stream>>>(pred, gt, ratio, slots, out);
}